// Round 13
// baseline (698.155 us; speedup 1.0000x reference)
//
#include <hip/hip_runtime.h>
#include <cstdint>
#include <cstddef>

using short8   = __attribute__((ext_vector_type(8))) short;
using f32x4    = __attribute__((ext_vector_type(4))) float;
using ushort4v = __attribute__((ext_vector_type(4))) unsigned short;

#define B_    32
#define N_    577
#define C_    768
#define H_    12
#define HD_   64
#define NPAD  640
#define MROWS 18464   // B*N
#define MPAD  18560   // 145*128
#define NQKV  2304    // 3*C
#define SCALE 0.125f
#define OUT0_ELTS 14180352   // B*N*C

static __device__ __forceinline__ unsigned short f2bf(float f) {
  union { float f; unsigned int u; } v; v.f = f;
  return (unsigned short)((v.u + 0x7FFFu + ((v.u >> 16) & 1u)) >> 16);
}

static __device__ __forceinline__ void gload_lds16(const unsigned short* g, unsigned short* l) {
  __builtin_amdgcn_global_load_lds(
      (const __attribute__((address_space(1))) unsigned int*)g,
      (__attribute__((address_space(3))) unsigned int*)l, 16, 0, 0);
}

// ---------------- fused f32 -> bf16 convert (x, Wqkv, Wproj in one grid) ----------------
__global__ __launch_bounds__(256) void cvt_all(
    const float* __restrict__ x, const float* __restrict__ wqkv,
    const float* __restrict__ wproj,
    unsigned short* __restrict__ xb, unsigned short* __restrict__ wqkvb,
    unsigned short* __restrict__ wprojb) {
  const int i = blockIdx.x * 256 + threadIdx.x;      // grid = 16152*256 = exact
  const int n1 = (B_ * N_ * C_) / 4;                 // 3,545,088
  const int n2 = n1 + (NQKV * C_) / 4;               // +442,368
  const float* src; unsigned short* dst; int j;
  if (i < n1)      { src = x;     dst = xb;     j = i; }
  else if (i < n2) { src = wqkv;  dst = wqkvb;  j = i - n1; }
  else             { src = wproj; dst = wprojb; j = i - n2; }
  f32x4 v = ((const f32x4*)src)[j];
  ushort4v o;
  o.x = f2bf(v.x); o.y = f2bf(v.y); o.z = f2bf(v.z); o.w = f2bf(v.w);
  ((ushort4v*)dst)[j] = o;
}

// ---------------- vtb tail zero ----------------
// Only vtb's last 64-col group (tokens 576..639 under the storage swizzle)
// ever meets exact-zero P slots in MFMA (0 * NaN = NaN hazard on the very
// first call, before the harness's finite 0xAA poison). Zero just that group:
// 24576 rows x 128 B = 3.1 MB. gemm_qkv writes token 576's chunks afterwards.
__global__ __launch_bounds__(256) void zero_vtb_tail(unsigned short* __restrict__ vtb) {
  const int i = blockIdx.x * 256 + threadIdx.x;      // grid = 768 (196608 chunks)
  const int row = i >> 3, c = i & 7;
  short8 z = {};
  *(short8*)(vtb + (size_t)row * NPAD + 576 + c * 8) = z;
}

// ---------------- QKV GEMM ----------------
// q/k/vT buffers are stored PRE-SWIZZLED: within each 64-row (or 64-col) attn
// tile, 16B chunk c of row r is stored at chunk position c^(r&7). attn then
// stages with fully-linear coalesced global reads and reads LDS conflict-free
// with the matching XOR. (The permutation lives in the buffer layout.)
__global__ __launch_bounds__(256) void gemm_qkv(
    const unsigned short* __restrict__ A,    // xb [MPAD][768]
    const unsigned short* __restrict__ Bw,   // wqkvb [2304][768]
    unsigned short* __restrict__ qb,         // [B*H][640][64]  (swizzled rows)
    unsigned short* __restrict__ kbuf,       // [B*H][640][64]  (swizzled rows)
    unsigned short* __restrict__ vtb)        // [B*H][64][640]  (swizzled per 64-col tile)
{
  __shared__ union {
    struct { unsigned short A[128 * 64]; unsigned short B[128 * 64]; } st;
    unsigned short ct[128 * 128];            // epilogue C-tile (bf16)
  } lds;
  const int mt = blockIdx.x, nt = blockIdx.y;
  const int tid = threadIdx.x;
  const int wave = tid >> 6, lane = tid & 63;
  const int wm = wave >> 1, wn = wave & 1;
  const int lq = lane & 15, grp = lane >> 4;

  f32x4 acc[4][4] = {};

  const int arowbase = mt * 128;
  const int browbase = nt * 128;
  const int srow = wave * 8 + (lane >> 3);
  const int scol = (lane & 7) * 8;

  for (int kblk = 0; kblk < 12; ++kblk) {
    const int koff = kblk * 64;
#pragma unroll
    for (int i = 0; i < 4; ++i) {
      gload_lds16(A  + (size_t)(arowbase + i * 32 + srow) * 768 + koff + scol,
                  &lds.st.A[(i * 32 + wave * 8) * 64]);
      gload_lds16(Bw + (size_t)(browbase + i * 32 + srow) * 768 + koff + scol,
                  &lds.st.B[(i * 32 + wave * 8) * 64]);
    }
    __syncthreads();
#pragma unroll
    for (int ks = 0; ks < 2; ++ks) {
      short8 af[4], bf[4];
#pragma unroll
      for (int mi = 0; mi < 4; ++mi)
        af[mi] = *(const short8*)&lds.st.A[(wm * 64 + mi * 16 + lq) * 64 + ks * 32 + grp * 8];
#pragma unroll
      for (int ni = 0; ni < 4; ++ni)
        bf[ni] = *(const short8*)&lds.st.B[(wn * 64 + ni * 16 + lq) * 64 + ks * 32 + grp * 8];
#pragma unroll
      for (int mi = 0; mi < 4; ++mi)
#pragma unroll
        for (int ni = 0; ni < 4; ++ni)
          acc[mi][ni] = __builtin_amdgcn_mfma_f32_16x16x32_bf16(af[mi], bf[ni], acc[mi][ni], 0, 0, 0);
    }
    __syncthreads();
  }

  const int s = nt / 6;   // section: 0=q 1=k 2=v (block-uniform)

  if (s < 2) {
    // ---- LDS-staged coalesced epilogue (q / k), dst chunk XOR-swizzled ----
#pragma unroll
    for (int mi = 0; mi < 4; ++mi)
#pragma unroll
      for (int ni = 0; ni < 4; ++ni) {
        const int col = wn * 64 + ni * 16 + lq;
#pragma unroll
        for (int j = 0; j < 4; ++j) {
          const int row = wm * 64 + mi * 16 + grp * 4 + j;
          const int slot = (col >> 3) ^ (row & 7);
          lds.ct[row * 128 + slot * 8 + (col & 7)] = f2bf(acc[mi][ni][j]);
        }
      }
    __syncthreads();
    unsigned short* dstbase = (s == 0) ? qb : kbuf;
    const int h0 = (nt - s * 6) * 2;   // first of the 2 heads this tile covers
#pragma unroll
    for (int p = 0; p < 4; ++p) {
      const int r  = p * 32 + (tid >> 3);   // C-tile row (0..127)
      const int cp = tid & 7;               // 8-col chunk within head
      const int m  = arowbase + r;
      const unsigned bb = (unsigned)m / 577u;
      const int t = m - (int)bb * 577;
      const bool valid = (m < MROWS);
      const int cpos = cp ^ (t & 7);        // storage swizzle (row = token t)
#pragma unroll
      for (int hh = 0; hh < 2; ++hh) {
        const int slot = ((hh * 8 + cp) ^ (r & 7));
        short8 val = *(const short8*)&lds.ct[r * 128 + slot * 8];
        if (valid) {
          unsigned short* dst = dstbase +
              (((size_t)(bb * H_ + h0 + hh) * NPAD + t) * HD_ + cpos * 8);
          *(short8*)dst = val;
        }
      }
    }
  } else {
    // ---- v^T scalar epilogue (store at swizzled column within 64-col tile) ----
#pragma unroll
    for (int mi = 0; mi < 4; ++mi) {
#pragma unroll
      for (int ni = 0; ni < 4; ++ni) {
        const int n = browbase + wn * 64 + ni * 16 + lq;
        const int rem = n - 1536;
        const int hh = rem >> 6, d = rem & 63;
#pragma unroll
        for (int j = 0; j < 4; ++j) {
          const int m = arowbase + wm * 64 + mi * 16 + grp * 4 + j;
          if (m < MROWS) {
            const unsigned bb = (unsigned)m / 577u;
            const int t = m - (int)bb * 577;
            const int tloc = t & 63;
            const int newcol = (t & ~63) + ((((tloc >> 3) ^ (d & 7)) << 3)) + (t & 7);
            vtb[((size_t)bb * H_ + hh) * HD_ * NPAD + (size_t)d * NPAD + newcol] =
                f2bf(acc[mi][ni][j]);
          }
        }
      }
    }
  }
}

// ---------------- Fused attention (v12, proven) ----------------
__global__ __launch_bounds__(256, 3) void attn_kernel(
    const unsigned short* __restrict__ qb,
    const unsigned short* __restrict__ kb,
    const unsigned short* __restrict__ vtb,
    const float* __restrict__ prev,
    float* __restrict__ scores_out,   // d_out + OUT0_ELTS
    unsigned short* __restrict__ ob)  // [MPAD][768] bf16
{
  const int qblk = blockIdx.x;   // 0..9
  const int bh   = blockIdx.y;   // 0..383
  const int tid  = threadIdx.x;
  const int wave = tid >> 6;
  const int lane = tid & 63;
  const int lq = lane & 15, grp = lane >> 4;

  const int b = bh / H_;
  const int h = bh - b * H_;

  const unsigned short* qp = qb  + (size_t)bh * NPAD * HD_;
  const unsigned short* kp = kb  + (size_t)bh * NPAD * HD_;
  const unsigned short* vp = vtb + (size_t)bh * HD_ * NPAD;

  const int qrow = qblk * 64 + wave * 16 + lq;
  const bool qvalid = (qrow < N_);
  const bool counted = (qblk < 9);   // block-uniform: counted-vmcnt is sound

  // own-row clamped pointer (used only by the peeled k=576 column)
  const float* prevrow_c = prev + ((size_t)bh * N_ + (qvalid ? qrow : (N_ - 1))) * N_;
  const float* prevbh = prev + (size_t)bh * N_ * N_;
  float* srow_base = scores_out + (size_t)bh * N_ * N_;

  __shared__ __attribute__((aligned(16))) unsigned short ldsK[2][4096];
  __shared__ __attribute__((aligned(16))) unsigned short ldsV[2][4096];
  __shared__ __attribute__((aligned(16))) float sslab[4][16][68];

  // Q fragment: qb rows are chunk-swizzled by (row&7) = (lq&7)
  short8 qf0, qf1;
  {
    const unsigned short* qr = qp + (size_t)qrow * HD_;
    qf0 = *(const short8*)(qr + ((grp)     ^ (lq & 7)) * 8);
    qf1 = *(const short8*)(qr + ((grp + 4) ^ (lq & 7)) * 8);
  }

  f32x4 oacc[4] = {};
  float lacc = 0.f;

  // linear staging: global buffers pre-swizzled -> straight contiguous copy
  const int srow8 = wave * 8 + (lane >> 3);   // 0..31
  const int scol8 = (lane & 7) * 8;
  auto stageKV = [&](int kblk, int bufi) {
    const int kbase = kblk * 64;
#pragma unroll
    for (int r = 0; r < 2; ++r) {
      gload_lds16(kp + (size_t)(kbase + r * 32 + srow8) * HD_ + scol8,
                  &ldsK[bufi][r * 2048 + wave * 512]);
      gload_lds16(vp + (size_t)(r * 32 + srow8) * NPAD + kbase + scol8,
                  &ldsV[bufi][r * 2048 + wave * 512]);
    }
  };

  // coalesced prev mapping (== scores store mapping):
  // row16 = q4*4 + (lane>>4), col0 = (lane&15)*4 -> 4 rows x 256B per instr
  const int rl16  = lane >> 4;           // 0..3
  const int col0l = (lane & 15) * 4;
  int roff[4];                            // row offsets, rows clamped to 576
#pragma unroll
  for (int q4 = 0; q4 < 4; ++q4) {
    int r = qblk * 64 + wave * 16 + q4 * 4 + rl16;
    if (r >= N_) r = N_ - 1;              // valid memory; values discarded
    roff[q4] = r * N_;
  }
  auto loadPrevC = [&](int kblk, f32x4 pv[4]) {
#pragma unroll
    for (int q4 = 0; q4 < 4; ++q4) {
      float tmp[4];
      __builtin_memcpy(tmp, prevbh + roff[q4] + kblk * 64 + col0l, 16);  // 4B-aligned
      pv[q4][0] = tmp[0]; pv[q4][1] = tmp[1]; pv[q4][2] = tmp[2]; pv[q4][3] = tmp[3];
    }
  };

  // swizzled fragment slots (ushort offsets within a row's 64 ushorts)
  const int sl0 = ((grp)     ^ (lq & 7)) * 8;
  const int sl1 = ((grp + 4) ^ (lq & 7)) * 8;

  f32x4 pvc[4], pvnc[4];
  stageKV(0, 0);
  asm volatile("" ::: "memory");
  loadPrevC(0, pvc);
  asm volatile("" ::: "memory");
  if (counted) asm volatile("s_waitcnt vmcnt(4)" ::: "memory");  // stage retired; prev floats
  else         asm volatile("s_waitcnt vmcnt(0)" ::: "memory");
  __builtin_amdgcn_s_barrier();
  __builtin_amdgcn_sched_barrier(0);

#pragma unroll 1
  for (int kblk = 0; kblk < 9; ++kblk) {
    const int cur = kblk & 1;
    const int kbase = kblk * 64;

    // issue next-tile stage + next prev loads first (full-iteration cover)
    stageKV(kblk + 1, cur ^ 1);
    asm volatile("" ::: "memory");     // pin: loads below stay below the stage
    if (kblk < 8) loadPrevC(kblk + 1, pvnc);
    asm volatile("" ::: "memory");     // pin: stores/compute stay below

    // S^T = K @ Q^T from LDS (per lane: col=q=lq, row=k-in-tile=grp*4+reg)
    f32x4 sacc[4] = {};
#pragma unroll
    for (int t = 0; t < 4; ++t) {
      const int row = (t * 16 + lq) * 64;
      short8 a0 = *(const short8*)&ldsK[cur][row + sl0];
      short8 a1 = *(const short8*)&ldsK[cur][row + sl1];
      sacc[t] = __builtin_amdgcn_mfma_f32_16x16x32_bf16(a0, qf0, sacc[t], 0, 0, 0);
      sacc[t] = __builtin_amdgcn_mfma_f32_16x16x32_bf16(a1, qf1, sacc[t], 0, 0, 0);
    }

    // raw scaled S -> slab ([q][k] layout, no prev yet)
#pragma unroll
    for (int t = 0; t < 4; ++t) {
      f32x4 sv;
#pragma unroll
      for (int r = 0; r < 4; ++r)
        sv[r] = sacc[t][r] * SCALE;
      *(f32x4*)&sslab[wave][lq][t * 16 + grp * 4] = sv;
    }

    // store-map pass: slab + prev -> global scores AND back to slab
#pragma unroll
    for (int q4 = 0; q4 < 4; ++q4) {
      const int row16 = q4 * 4 + rl16;
      const int qrow_s = qblk * 64 + wave * 16 + row16;
      f32x4 vals = *(const f32x4*)&sslab[wave][row16][col0l];
      vals += pvc[q4];
      if (qrow_s < N_)
        __builtin_memcpy(srow_base + (size_t)qrow_s * N_ + kbase + col0l, &vals, 16);
      *(f32x4*)&sslab[wave][row16][col0l] = vals;
    }

    // P fragments: read own q-row (now scores-with-prev), exp, pack bf16
    short8 pf0, pf1;
    {
      const float* sr = &sslab[wave][lq][0];
      f32x4 x0 = *(const f32x4*)(sr + grp * 8);
      f32x4 x1 = *(const f32x4*)(sr + grp * 8 + 4);
      f32x4 x2 = *(const f32x4*)(sr + 32 + grp * 8);
      f32x4 x3 = *(const f32x4*)(sr + 32 + grp * 8 + 4);
      float e[16];
#pragma unroll
      for (int j = 0; j < 4; ++j) {
        e[j]      = __expf(x0[j]);
        e[4 + j]  = __expf(x1[j]);
        e[8 + j]  = __expf(x2[j]);
        e[12 + j] = __expf(x3[j]);
      }
#pragma unroll
      for (int j = 0; j < 16; ++j) lacc += e[j];
      ushort4v pa, pb2, pc, pd;
#pragma unroll
      for (int j = 0; j < 4; ++j) {
        ((unsigned short*)&pa)[j]  = f2bf(e[j]);
        ((unsigned short*)&pb2)[j] = f2bf(e[4 + j]);
        ((unsigned short*)&pc)[j]  = f2bf(e[8 + j]);
        ((unsigned short*)&pd)[j]  = f2bf(e[12 + j]);
      }
      union { struct { ushort4v a, b; } s; short8 v; } u0, u1;
      u0.s.a = pa; u0.s.b = pb2; pf0 = u0.v;
      u1.s.a = pc; u1.s.b = pd;  pf1 = u1.v;
    }

    // O^T += V^T @ P^T from LDS
#pragma unroll
    for (int dt = 0; dt < 4; ++dt) {
      const int row = (dt * 16 + lq) * 64;
      short8 v0 = *(const short8*)&ldsV[cur][row + sl0];
      short8 v1 = *(const short8*)&ldsV[cur][row + sl1];
      oacc[dt] = __builtin_amdgcn_mfma_f32_16x16x32_bf16(v0, pf0, oacc[dt], 0, 0, 0);
      oacc[dt] = __builtin_amdgcn_mfma_f32_16x16x32_bf16(v1, pf1, oacc[dt], 0, 0, 0);
    }

    // sync: counted blocks retire only the stage (prev+stores float);
    // qblk==9 blocks full-drain (their store count is exec-mask-dependent).
    if (counted) {
      if (kblk == 8) asm volatile("s_waitcnt vmcnt(4)" ::: "memory");
      else           asm volatile("s_waitcnt vmcnt(8)" ::: "memory");
    } else {
      asm volatile("s_waitcnt vmcnt(0)" ::: "memory");
    }
    __builtin_amdgcn_s_barrier();
    __builtin_amdgcn_sched_barrier(0);
#pragma unroll
    for (int i = 0; i < 4; ++i) pvc[i] = pvnc[i];
  }

  // ---- peeled k-tile 9 (kbase=576): single valid column k=576 ----
  {
    f32x4 s0 = {};
    {
      const int row = lq * 64;
      short8 a0 = *(const short8*)&ldsK[1][row + sl0];
      short8 a1 = *(const short8*)&ldsK[1][row + sl1];
      s0 = __builtin_amdgcn_mfma_f32_16x16x32_bf16(a0, qf0, s0, 0, 0, 0);
      s0 = __builtin_amdgcn_mfma_f32_16x16x32_bf16(a1, qf1, s0, 0, 0, 0);
    }
    const float sval9 = s0[0] * SCALE + prevrow_c[576];
    const float e9 = (grp == 0) ? __expf(sval9) : 0.f;
    lacc += e9;
    short8 pf0 = {};
    ((unsigned short*)&pf0)[0] = f2bf(e9);   // f2bf(0)=0 for grp!=0
#pragma unroll
    for (int dt = 0; dt < 4; ++dt) {
      const int row = (dt * 16 + lq) * 64;
      short8 v0 = *(const short8*)&ldsV[1][row + sl0];
      oacc[dt] = __builtin_amdgcn_mfma_f32_16x16x32_bf16(v0, pf0, oacc[dt], 0, 0, 0);
    }
    if (grp == 0 && qvalid)
      srow_base[(size_t)qrow * N_ + 576] = sval9;
  }

  // deferred l-reduce: lanes ^16, ^32 hold the other k-subsets of the same q-row
  lacc += __shfl_xor(lacc, 16, 64);
  lacc += __shfl_xor(lacc, 32, 64);

  if (qvalid) {
    const float rl = 1.0f / lacc;
    unsigned short* orow = ob + (size_t)(b * N_ + qrow) * C_ + h * HD_;
#pragma unroll
    for (int dt = 0; dt < 4; ++dt) {
      ushort4v ow;
      ow.x = f2bf(oacc[dt][0] * rl); ow.y = f2bf(oacc[dt][1] * rl);
      ow.z = f2bf(oacc[dt][2] * rl); ow.w = f2bf(oacc[dt][3] * rl);
      *(ushort4v*)(orow + dt * 16 + grp * 4) = ow;
    }
  }
}

// ---------------- Proj GEMM: out0[m,n] = sum_k ob[m,k]*Wproj[n,k] + bias[n] ----------------
// LDS-staged f32 epilogue (r9 pattern): two 32KB column-halves, XOR-chunk
// swizzle; stores are aligned dwordx4, 4 rows x 256B contiguous per instr
// (replaces 64 scattered scalar-dword stores per thread).
__global__ __launch_bounds__(256) void gemm_proj(
    const unsigned short* __restrict__ A,    // ob [MPAD][768]
    const unsigned short* __restrict__ Bw,   // wprojb [768][768]
    const float* __restrict__ bias,
    float* __restrict__ out0)
{
  __shared__ union {
    struct { unsigned short A[128 * 64]; unsigned short B[128 * 64]; } st;
    float ct32[128 * 64];                    // epilogue half-tile (f32, 32KB)
  } lds;
  const int mt = blockIdx.x, nt = blockIdx.y;
  const int tid = threadIdx.x;
  const int wave = tid >> 6, lane = tid & 63;
  const int wm = wave >> 1, wn = wave & 1;
  const int lq = lane & 15, grp = lane >> 4;

  f32x4 acc[4][4] = {};

  const int arowbase = mt * 128;
  const int browbase = nt * 128;
  const int srow = wave * 8 + (lane >> 3);
  const int scol = (lane & 7) * 8;

  for (int kblk = 0; kblk < 12; ++kblk) {
    const int koff = kblk * 64;
#pragma unroll
    for (int i = 0; i < 4; ++i) {
      gload_lds16(A  + (size_t)(arowbase + i * 32 + srow) * 768 + koff + scol,
                  &lds.st.A[(i * 32 + wave * 8) * 64]);
      gload_lds16(Bw + (size_t)(browbase + i * 32 + srow) * 768 + koff + scol,
                  &lds.st.B[(i * 32 + wave * 8) * 64]);
    }
    __syncthreads();
#pragma unroll
    for (int ks = 0; ks < 2; ++ks) {
      short8 af[4], bf[4];
#pragma unroll
      for (int mi = 0; mi < 4; ++mi)
        af[mi] = *(const short8*)&lds.st.A[(wm * 64 + mi * 16 + lq) * 64 + ks * 32 + grp * 8];
#pragma unroll
      for (int ni = 0; ni < 4; ++ni)
        bf[ni] = *(const short8*)&lds.st.B[(wn * 64 + ni * 16 + lq) * 64 + ks * 32 + grp * 8];
#pragma unroll
      for (int mi = 0; mi < 4; ++mi)
#pragma unroll
        for (int ni = 0; ni < 4; ++ni)
          acc[mi][ni] = __builtin_amdgcn_mfma_f32_16x16x32_bf16(af[mi], bf[ni], acc[mi][ni], 0, 0, 0);
    }
    __syncthreads();
  }

  // ---- staged epilogue: half hh2 holds cols [hh2*64, hh2*64+64) ----
#pragma unroll
  for (int hh2 = 0; hh2 < 2; ++hh2) {
    __syncthreads();   // k-loop LDS / previous half's reads are done
    if (wn == hh2) {
#pragma unroll
      for (int ni = 0; ni < 4; ++ni) {
        const int colh = ni * 16 + lq;       // 0..63 within this half
        const int cc = colh >> 2, el = colh & 3;
        const float bv = bias[browbase + hh2 * 64 + colh];
#pragma unroll
        for (int mi = 0; mi < 4; ++mi)
#pragma unroll
          for (int j = 0; j < 4; ++j) {
            const int row = wm * 64 + mi * 16 + grp * 4 + j;
            lds.ct32[row * 64 + ((cc ^ (row & 7)) << 2) + el] = acc[mi][ni][j] + bv;
          }
      }
    }
    __syncthreads();
#pragma unroll
    for (int p = 0; p < 8; ++p) {
      const int row = p * 16 + wave * 4 + (lane >> 4);   // 0..127
      const int cc = lane & 15;
      const int m = arowbase + row;
      f32x4 val = *(const f32x4*)&lds.ct32[row * 64 + ((cc ^ (row & 7)) << 2)];
      if (m < MROWS)
        *(f32x4*)&out0[(size_t)m * C_ + browbase + hh2 * 64 + cc * 4] = val;
    }
  }
}

// ---------------- launch ----------------
extern "C" void kernel_launch(void* const* d_in, const int* in_sizes, int n_in,
                              void* d_out, int out_size, void* d_ws, size_t ws_size,
                              hipStream_t stream) {
  const float* x     = (const float*)d_in[0];
  const float* prev  = (const float*)d_in[1];
  const float* Wqkv  = (const float*)d_in[2];
  const float* Wproj = (const float*)d_in[3];
  const float* bproj = (const float*)d_in[4];
  float* out = (float*)d_out;

  char* ws = (char*)d_ws;
  size_t off = 0;
  auto alloc = [&](size_t bytes) {
    void* p = ws + off;
    off += (bytes + 255) & ~(size_t)255;
    return p;
  };
  unsigned short* xb     = (unsigned short*)alloc((size_t)MPAD * 768 * 2);
  unsigned short* wqkvb  = (unsigned short*)alloc((size_t)NQKV * 768 * 2);
  unsigned short* wprojb = (unsigned short*)alloc((size_t)768 * 768 * 2);
  unsigned short* qb     = (unsigned short*)alloc((size_t)B_ * H_ * NPAD * HD_ * 2);
  unsigned short* kbuf   = (unsigned short*)alloc((size_t)B_ * H_ * NPAD * HD_ * 2);
  unsigned short* vtb    = (unsigned short*)alloc((size_t)B_ * H_ * HD_ * NPAD * 2);
  unsigned short* ob     = (unsigned short*)alloc((size_t)MPAD * 768 * 2);
  (void)ob;

  // Zero only vtb's tail 64-col group (3.1 MB): the sole region that meets
  // exact-zero P slots in MFMA (0*NaN hazard on the pre-poison first call).
  // All other buffer pads are protected by MFMA row/column independence and
  // by the harness's 0xAA poison being finite in bf16.
  zero_vtb_tail<<<768, 256, 0, stream>>>(vtb);

  cvt_all<<<16152, 256, 0, stream>>>(x, Wqkv, Wproj, xb, wqkvb, wprojb);

  gemm_qkv<<<dim3(MPAD / 128, NQKV / 128), 256, 0, stream>>>(xb, wqkvb, qb, kbuf, vtb);

  attn_kernel<<<dim3(10, B_ * H_), 256, 0, stream>>>(qb, kbuf, vtb, prev,
                                                     out + OUT0_ELTS, ob);

  gemm_proj<<<dim3(MPAD / 128, C_ / 128), 256, 0, stream>>>(ob, wprojb, bproj, out);
}

// Round 14
// 580.630 us; speedup vs baseline: 1.2024x; 1.2024x over previous
//
#include <hip/hip_runtime.h>
#include <cstdint>
#include <cstddef>

using short8   = __attribute__((ext_vector_type(8))) short;
using f32x4    = __attribute__((ext_vector_type(4))) float;
using ushort4v = __attribute__((ext_vector_type(4))) unsigned short;

#define B_    32
#define N_    577
#define C_    768
#define H_    12
#define HD_   64
#define NPAD  640
#define MROWS 18464   // B*N
#define MPAD  18560   // 145*128
#define NQKV  2304    // 3*C
#define SCALE 0.125f
#define OUT0_ELTS 14180352   // B*N*C

static __device__ __forceinline__ unsigned short f2bf(float f) {
  union { float f; unsigned int u; } v; v.f = f;
  return (unsigned short)((v.u + 0x7FFFu + ((v.u >> 16) & 1u)) >> 16);
}

static __device__ __forceinline__ void gload_lds16(const unsigned short* g, unsigned short* l) {
  __builtin_amdgcn_global_load_lds(
      (const __attribute__((address_space(1))) unsigned int*)g,
      (__attribute__((address_space(3))) unsigned int*)l, 16, 0, 0);
}

// ---------------- f32 -> bf16 convert ----------------
__global__ __launch_bounds__(256) void cvt_f32_bf16(const float* __restrict__ src,
                                                    unsigned short* __restrict__ dst, int n4) {
  int i = blockIdx.x * 256 + threadIdx.x;
  if (i >= n4) return;
  f32x4 v = ((const f32x4*)src)[i];
  ushort4v o;
  o.x = f2bf(v.x); o.y = f2bf(v.y); o.z = f2bf(v.z); o.w = f2bf(v.w);
  ((ushort4v*)dst)[i] = o;
}

// ---------------- vtb tail zero ----------------
// Only vtb's last 64-col group (tokens 576..639 under the storage swizzle)
// ever meets exact-zero P slots in MFMA (0 * NaN = NaN hazard). Every other
// pad region is arithmetically discarded (MFMA dot-product row/column
// independence + guards). 24576 rows x 128 B = 3.1 MB; gemm_qkv writes token
// 576's chunks afterwards.
__global__ __launch_bounds__(256) void zero_vtb_tail(unsigned short* __restrict__ vtb) {
  const int i = blockIdx.x * 256 + threadIdx.x;      // grid = 768 (196608 chunks)
  const int row = i >> 3, c = i & 7;
  short8 z = {};
  *(short8*)(vtb + (size_t)row * NPAD + 576 + c * 8) = z;
}

// ---------------- QKV GEMM ----------------
// q/k/vT buffers are stored PRE-SWIZZLED: within each 64-row (or 64-col) attn
// tile, 16B chunk c of row r is stored at chunk position c^(r&7). attn then
// stages with fully-linear coalesced global reads and reads LDS conflict-free
// with the matching XOR. (The permutation lives in the buffer layout.)
__global__ __launch_bounds__(256) void gemm_qkv(
    const unsigned short* __restrict__ A,    // xb [MPAD][768]
    const unsigned short* __restrict__ Bw,   // wqkvb [2304][768]
    unsigned short* __restrict__ qb,         // [B*H][640][64]  (swizzled rows)
    unsigned short* __restrict__ kbuf,       // [B*H][640][64]  (swizzled rows)
    unsigned short* __restrict__ vtb)        // [B*H][64][640]  (swizzled per 64-col tile)
{
  __shared__ union {
    struct { unsigned short A[128 * 64]; unsigned short B[128 * 64]; } st;
    unsigned short ct[128 * 128];            // epilogue C-tile (bf16)
  } lds;
  const int mt = blockIdx.x, nt = blockIdx.y;
  const int tid = threadIdx.x;
  const int wave = tid >> 6, lane = tid & 63;
  const int wm = wave >> 1, wn = wave & 1;
  const int lq = lane & 15, grp = lane >> 4;

  f32x4 acc[4][4] = {};

  const int arowbase = mt * 128;
  const int browbase = nt * 128;
  const int srow = wave * 8 + (lane >> 3);
  const int scol = (lane & 7) * 8;

  for (int kblk = 0; kblk < 12; ++kblk) {
    const int koff = kblk * 64;
#pragma unroll
    for (int i = 0; i < 4; ++i) {
      gload_lds16(A  + (size_t)(arowbase + i * 32 + srow) * 768 + koff + scol,
                  &lds.st.A[(i * 32 + wave * 8) * 64]);
      gload_lds16(Bw + (size_t)(browbase + i * 32 + srow) * 768 + koff + scol,
                  &lds.st.B[(i * 32 + wave * 8) * 64]);
    }
    __syncthreads();
#pragma unroll
    for (int ks = 0; ks < 2; ++ks) {
      short8 af[4], bf[4];
#pragma unroll
      for (int mi = 0; mi < 4; ++mi)
        af[mi] = *(const short8*)&lds.st.A[(wm * 64 + mi * 16 + lq) * 64 + ks * 32 + grp * 8];
#pragma unroll
      for (int ni = 0; ni < 4; ++ni)
        bf[ni] = *(const short8*)&lds.st.B[(wn * 64 + ni * 16 + lq) * 64 + ks * 32 + grp * 8];
#pragma unroll
      for (int mi = 0; mi < 4; ++mi)
#pragma unroll
        for (int ni = 0; ni < 4; ++ni)
          acc[mi][ni] = __builtin_amdgcn_mfma_f32_16x16x32_bf16(af[mi], bf[ni], acc[mi][ni], 0, 0, 0);
    }
    __syncthreads();
  }

  const int s = nt / 6;   // section: 0=q 1=k 2=v (block-uniform)

  if (s < 2) {
    // ---- LDS-staged coalesced epilogue (q / k), dst chunk XOR-swizzled ----
#pragma unroll
    for (int mi = 0; mi < 4; ++mi)
#pragma unroll
      for (int ni = 0; ni < 4; ++ni) {
        const int col = wn * 64 + ni * 16 + lq;
#pragma unroll
        for (int j = 0; j < 4; ++j) {
          const int row = wm * 64 + mi * 16 + grp * 4 + j;
          const int slot = (col >> 3) ^ (row & 7);
          lds.ct[row * 128 + slot * 8 + (col & 7)] = f2bf(acc[mi][ni][j]);
        }
      }
    __syncthreads();
    unsigned short* dstbase = (s == 0) ? qb : kbuf;
    const int h0 = (nt - s * 6) * 2;   // first of the 2 heads this tile covers
#pragma unroll
    for (int p = 0; p < 4; ++p) {
      const int r  = p * 32 + (tid >> 3);   // C-tile row (0..127)
      const int cp = tid & 7;               // 8-col chunk within head
      const int m  = arowbase + r;
      const unsigned bb = (unsigned)m / 577u;
      const int t = m - (int)bb * 577;
      const bool valid = (m < MROWS);
      const int cpos = cp ^ (t & 7);        // storage swizzle (row = token t)
#pragma unroll
      for (int hh = 0; hh < 2; ++hh) {
        const int slot = ((hh * 8 + cp) ^ (r & 7));
        short8 val = *(const short8*)&lds.ct[r * 128 + slot * 8];
        if (valid) {
          unsigned short* dst = dstbase +
              (((size_t)(bb * H_ + h0 + hh) * NPAD + t) * HD_ + cpos * 8);
          *(short8*)dst = val;
        }
      }
    }
  } else {
    // ---- v^T scalar epilogue (store at swizzled column within 64-col tile) ----
#pragma unroll
    for (int mi = 0; mi < 4; ++mi) {
#pragma unroll
      for (int ni = 0; ni < 4; ++ni) {
        const int n = browbase + wn * 64 + ni * 16 + lq;
        const int rem = n - 1536;
        const int hh = rem >> 6, d = rem & 63;
#pragma unroll
        for (int j = 0; j < 4; ++j) {
          const int m = arowbase + wm * 64 + mi * 16 + grp * 4 + j;
          if (m < MROWS) {
            const unsigned bb = (unsigned)m / 577u;
            const int t = m - (int)bb * 577;
            const int tloc = t & 63;
            const int newcol = (t & ~63) + ((((tloc >> 3) ^ (d & 7)) << 3)) + (t & 7);
            vtb[((size_t)bb * H_ + hh) * HD_ * NPAD + (size_t)d * NPAD + newcol] =
                f2bf(acc[mi][ni][j]);
          }
        }
      }
    }
  }
}

// ---------------- Fused attention (v12, proven) ----------------
__global__ __launch_bounds__(256, 3) void attn_kernel(
    const unsigned short* __restrict__ qb,
    const unsigned short* __restrict__ kb,
    const unsigned short* __restrict__ vtb,
    const float* __restrict__ prev,
    float* __restrict__ scores_out,   // d_out + OUT0_ELTS
    unsigned short* __restrict__ ob)  // [MPAD][768] bf16
{
  const int qblk = blockIdx.x;   // 0..9
  const int bh   = blockIdx.y;   // 0..383
  const int tid  = threadIdx.x;
  const int wave = tid >> 6;
  const int lane = tid & 63;
  const int lq = lane & 15, grp = lane >> 4;

  const int b = bh / H_;
  const int h = bh - b * H_;

  const unsigned short* qp = qb  + (size_t)bh * NPAD * HD_;
  const unsigned short* kp = kb  + (size_t)bh * NPAD * HD_;
  const unsigned short* vp = vtb + (size_t)bh * HD_ * NPAD;

  const int qrow = qblk * 64 + wave * 16 + lq;
  const bool qvalid = (qrow < N_);
  const bool counted = (qblk < 9);   // block-uniform: counted-vmcnt is sound

  // own-row clamped pointer (used only by the peeled k=576 column)
  const float* prevrow_c = prev + ((size_t)bh * N_ + (qvalid ? qrow : (N_ - 1))) * N_;
  const float* prevbh = prev + (size_t)bh * N_ * N_;
  float* srow_base = scores_out + (size_t)bh * N_ * N_;

  __shared__ __attribute__((aligned(16))) unsigned short ldsK[2][4096];
  __shared__ __attribute__((aligned(16))) unsigned short ldsV[2][4096];
  __shared__ __attribute__((aligned(16))) float sslab[4][16][68];

  // Q fragment: qb rows are chunk-swizzled by (row&7) = (lq&7)
  short8 qf0, qf1;
  {
    const unsigned short* qr = qp + (size_t)qrow * HD_;
    qf0 = *(const short8*)(qr + ((grp)     ^ (lq & 7)) * 8);
    qf1 = *(const short8*)(qr + ((grp + 4) ^ (lq & 7)) * 8);
  }

  f32x4 oacc[4] = {};
  float lacc = 0.f;

  // linear staging: global buffers pre-swizzled -> straight contiguous copy
  const int srow8 = wave * 8 + (lane >> 3);   // 0..31
  const int scol8 = (lane & 7) * 8;
  auto stageKV = [&](int kblk, int bufi) {
    const int kbase = kblk * 64;
#pragma unroll
    for (int r = 0; r < 2; ++r) {
      gload_lds16(kp + (size_t)(kbase + r * 32 + srow8) * HD_ + scol8,
                  &ldsK[bufi][r * 2048 + wave * 512]);
      gload_lds16(vp + (size_t)(r * 32 + srow8) * NPAD + kbase + scol8,
                  &ldsV[bufi][r * 2048 + wave * 512]);
    }
  };

  // coalesced prev mapping (== scores store mapping):
  // row16 = q4*4 + (lane>>4), col0 = (lane&15)*4 -> 4 rows x 256B per instr
  const int rl16  = lane >> 4;           // 0..3
  const int col0l = (lane & 15) * 4;
  int roff[4];                            // row offsets, rows clamped to 576
#pragma unroll
  for (int q4 = 0; q4 < 4; ++q4) {
    int r = qblk * 64 + wave * 16 + q4 * 4 + rl16;
    if (r >= N_) r = N_ - 1;              // valid memory; values discarded
    roff[q4] = r * N_;
  }
  auto loadPrevC = [&](int kblk, f32x4 pv[4]) {
#pragma unroll
    for (int q4 = 0; q4 < 4; ++q4) {
      float tmp[4];
      __builtin_memcpy(tmp, prevbh + roff[q4] + kblk * 64 + col0l, 16);  // 4B-aligned
      pv[q4][0] = tmp[0]; pv[q4][1] = tmp[1]; pv[q4][2] = tmp[2]; pv[q4][3] = tmp[3];
    }
  };

  // swizzled fragment slots (ushort offsets within a row's 64 ushorts)
  const int sl0 = ((grp)     ^ (lq & 7)) * 8;
  const int sl1 = ((grp + 4) ^ (lq & 7)) * 8;

  f32x4 pvc[4], pvnc[4];
  stageKV(0, 0);
  asm volatile("" ::: "memory");
  loadPrevC(0, pvc);
  asm volatile("" ::: "memory");
  if (counted) asm volatile("s_waitcnt vmcnt(4)" ::: "memory");  // stage retired; prev floats
  else         asm volatile("s_waitcnt vmcnt(0)" ::: "memory");
  __builtin_amdgcn_s_barrier();
  __builtin_amdgcn_sched_barrier(0);

#pragma unroll 1
  for (int kblk = 0; kblk < 9; ++kblk) {
    const int cur = kblk & 1;
    const int kbase = kblk * 64;

    // issue next-tile stage + next prev loads first (full-iteration cover)
    stageKV(kblk + 1, cur ^ 1);
    asm volatile("" ::: "memory");     // pin: loads below stay below the stage
    if (kblk < 8) loadPrevC(kblk + 1, pvnc);
    asm volatile("" ::: "memory");     // pin: stores/compute stay below

    // S^T = K @ Q^T from LDS (per lane: col=q=lq, row=k-in-tile=grp*4+reg)
    f32x4 sacc[4] = {};
#pragma unroll
    for (int t = 0; t < 4; ++t) {
      const int row = (t * 16 + lq) * 64;
      short8 a0 = *(const short8*)&ldsK[cur][row + sl0];
      short8 a1 = *(const short8*)&ldsK[cur][row + sl1];
      sacc[t] = __builtin_amdgcn_mfma_f32_16x16x32_bf16(a0, qf0, sacc[t], 0, 0, 0);
      sacc[t] = __builtin_amdgcn_mfma_f32_16x16x32_bf16(a1, qf1, sacc[t], 0, 0, 0);
    }

    // raw scaled S -> slab ([q][k] layout, no prev yet)
#pragma unroll
    for (int t = 0; t < 4; ++t) {
      f32x4 sv;
#pragma unroll
      for (int r = 0; r < 4; ++r)
        sv[r] = sacc[t][r] * SCALE;
      *(f32x4*)&sslab[wave][lq][t * 16 + grp * 4] = sv;
    }

    // store-map pass: slab + prev -> global scores AND back to slab
#pragma unroll
    for (int q4 = 0; q4 < 4; ++q4) {
      const int row16 = q4 * 4 + rl16;
      const int qrow_s = qblk * 64 + wave * 16 + row16;
      f32x4 vals = *(const f32x4*)&sslab[wave][row16][col0l];
      vals += pvc[q4];
      if (qrow_s < N_)
        __builtin_memcpy(srow_base + (size_t)qrow_s * N_ + kbase + col0l, &vals, 16);
      *(f32x4*)&sslab[wave][row16][col0l] = vals;
    }

    // P fragments: read own q-row (now scores-with-prev), exp, pack bf16
    short8 pf0, pf1;
    {
      const float* sr = &sslab[wave][lq][0];
      f32x4 x0 = *(const f32x4*)(sr + grp * 8);
      f32x4 x1 = *(const f32x4*)(sr + grp * 8 + 4);
      f32x4 x2 = *(const f32x4*)(sr + 32 + grp * 8);
      f32x4 x3 = *(const f32x4*)(sr + 32 + grp * 8 + 4);
      float e[16];
#pragma unroll
      for (int j = 0; j < 4; ++j) {
        e[j]      = __expf(x0[j]);
        e[4 + j]  = __expf(x1[j]);
        e[8 + j]  = __expf(x2[j]);
        e[12 + j] = __expf(x3[j]);
      }
#pragma unroll
      for (int j = 0; j < 16; ++j) lacc += e[j];
      ushort4v pa, pb2, pc, pd;
#pragma unroll
      for (int j = 0; j < 4; ++j) {
        ((unsigned short*)&pa)[j]  = f2bf(e[j]);
        ((unsigned short*)&pb2)[j] = f2bf(e[4 + j]);
        ((unsigned short*)&pc)[j]  = f2bf(e[8 + j]);
        ((unsigned short*)&pd)[j]  = f2bf(e[12 + j]);
      }
      union { struct { ushort4v a, b; } s; short8 v; } u0, u1;
      u0.s.a = pa; u0.s.b = pb2; pf0 = u0.v;
      u1.s.a = pc; u1.s.b = pd;  pf1 = u1.v;
    }

    // O^T += V^T @ P^T from LDS
#pragma unroll
    for (int dt = 0; dt < 4; ++dt) {
      const int row = (dt * 16 + lq) * 64;
      short8 v0 = *(const short8*)&ldsV[cur][row + sl0];
      short8 v1 = *(const short8*)&ldsV[cur][row + sl1];
      oacc[dt] = __builtin_amdgcn_mfma_f32_16x16x32_bf16(v0, pf0, oacc[dt], 0, 0, 0);
      oacc[dt] = __builtin_amdgcn_mfma_f32_16x16x32_bf16(v1, pf1, oacc[dt], 0, 0, 0);
    }

    // sync: counted blocks retire only the stage (prev+stores float);
    // qblk==9 blocks full-drain (their store count is exec-mask-dependent).
    if (counted) {
      if (kblk == 8) asm volatile("s_waitcnt vmcnt(4)" ::: "memory");
      else           asm volatile("s_waitcnt vmcnt(8)" ::: "memory");
    } else {
      asm volatile("s_waitcnt vmcnt(0)" ::: "memory");
    }
    __builtin_amdgcn_s_barrier();
    __builtin_amdgcn_sched_barrier(0);
#pragma unroll
    for (int i = 0; i < 4; ++i) pvc[i] = pvnc[i];
  }

  // ---- peeled k-tile 9 (kbase=576): single valid column k=576 ----
  {
    f32x4 s0 = {};
    {
      const int row = lq * 64;
      short8 a0 = *(const short8*)&ldsK[1][row + sl0];
      short8 a1 = *(const short8*)&ldsK[1][row + sl1];
      s0 = __builtin_amdgcn_mfma_f32_16x16x32_bf16(a0, qf0, s0, 0, 0, 0);
      s0 = __builtin_amdgcn_mfma_f32_16x16x32_bf16(a1, qf1, s0, 0, 0, 0);
    }
    const float sval9 = s0[0] * SCALE + prevrow_c[576];
    const float e9 = (grp == 0) ? __expf(sval9) : 0.f;
    lacc += e9;
    short8 pf0 = {};
    ((unsigned short*)&pf0)[0] = f2bf(e9);   // f2bf(0)=0 for grp!=0
#pragma unroll
    for (int dt = 0; dt < 4; ++dt) {
      const int row = (dt * 16 + lq) * 64;
      short8 v0 = *(const short8*)&ldsV[1][row + sl0];
      oacc[dt] = __builtin_amdgcn_mfma_f32_16x16x32_bf16(v0, pf0, oacc[dt], 0, 0, 0);
    }
    if (grp == 0 && qvalid)
      srow_base[(size_t)qrow * N_ + 576] = sval9;
  }

  // deferred l-reduce: lanes ^16, ^32 hold the other k-subsets of the same q-row
  lacc += __shfl_xor(lacc, 16, 64);
  lacc += __shfl_xor(lacc, 32, 64);

  if (qvalid) {
    const float rl = 1.0f / lacc;
    unsigned short* orow = ob + (size_t)(b * N_ + qrow) * C_ + h * HD_;
#pragma unroll
    for (int dt = 0; dt < 4; ++dt) {
      ushort4v ow;
      ow.x = f2bf(oacc[dt][0] * rl); ow.y = f2bf(oacc[dt][1] * rl);
      ow.z = f2bf(oacc[dt][2] * rl); ow.w = f2bf(oacc[dt][3] * rl);
      *(ushort4v*)(orow + dt * 16 + grp * 4) = ow;
    }
  }
}

// ---------------- Proj GEMM: out0[m,n] = sum_k ob[m,k]*Wproj[n,k] + bias[n] ----------------
__global__ __launch_bounds__(256) void gemm_proj(
    const unsigned short* __restrict__ A,    // ob [MPAD][768]
    const unsigned short* __restrict__ Bw,   // wprojb [768][768]
    const float* __restrict__ bias,
    float* __restrict__ out0)
{
  __shared__ unsigned short As[128 * 64];
  __shared__ unsigned short Bs[128 * 64];
  const int mt = blockIdx.x, nt = blockIdx.y;
  const int tid = threadIdx.x;
  const int wave = tid >> 6, lane = tid & 63;
  const int wm = wave >> 1, wn = wave & 1;
  const int lq = lane & 15, grp = lane >> 4;

  f32x4 acc[4][4] = {};

  const int arowbase = mt * 128;
  const int browbase = nt * 128;
  const int srow = wave * 8 + (lane >> 3);
  const int scol = (lane & 7) * 8;

  for (int kblk = 0; kblk < 12; ++kblk) {
    const int koff = kblk * 64;
#pragma unroll
    for (int i = 0; i < 4; ++i) {
      gload_lds16(A  + (size_t)(arowbase + i * 32 + srow) * 768 + koff + scol,
                  &As[(i * 32 + wave * 8) * 64]);
      gload_lds16(Bw + (size_t)(browbase + i * 32 + srow) * 768 + koff + scol,
                  &Bs[(i * 32 + wave * 8) * 64]);
    }
    __syncthreads();
#pragma unroll
    for (int ks = 0; ks < 2; ++ks) {
      short8 af[4], bf[4];
#pragma unroll
      for (int mi = 0; mi < 4; ++mi)
        af[mi] = *(const short8*)&As[(wm * 64 + mi * 16 + lq) * 64 + ks * 32 + grp * 8];
#pragma unroll
      for (int ni = 0; ni < 4; ++ni)
        bf[ni] = *(const short8*)&Bs[(wn * 64 + ni * 16 + lq) * 64 + ks * 32 + grp * 8];
#pragma unroll
      for (int mi = 0; mi < 4; ++mi)
#pragma unroll
        for (int ni = 0; ni < 4; ++ni)
          acc[mi][ni] = __builtin_amdgcn_mfma_f32_16x16x32_bf16(af[mi], bf[ni], acc[mi][ni], 0, 0, 0);
    }
    __syncthreads();
  }

#pragma unroll
  for (int ni = 0; ni < 4; ++ni) {
    const int n = browbase + wn * 64 + ni * 16 + lq;
    const float bv = bias[n];
#pragma unroll
    for (int mi = 0; mi < 4; ++mi) {
#pragma unroll
      for (int j = 0; j < 4; ++j) {
        const int m = arowbase + wm * 64 + mi * 16 + grp * 4 + j;
        if (m < MROWS) out0[(size_t)m * C_ + n] = acc[mi][ni][j] + bv;
      }
    }
  }
}

// ---------------- launch ----------------
extern "C" void kernel_launch(void* const* d_in, const int* in_sizes, int n_in,
                              void* d_out, int out_size, void* d_ws, size_t ws_size,
                              hipStream_t stream) {
  const float* x     = (const float*)d_in[0];
  const float* prev  = (const float*)d_in[1];
  const float* Wqkv  = (const float*)d_in[2];
  const float* Wproj = (const float*)d_in[3];
  const float* bproj = (const float*)d_in[4];
  float* out = (float*)d_out;

  char* ws = (char*)d_ws;
  size_t off = 0;
  auto alloc = [&](size_t bytes) {
    void* p = ws + off;
    off += (bytes + 255) & ~(size_t)255;
    return p;
  };
  unsigned short* xb     = (unsigned short*)alloc((size_t)MPAD * 768 * 2);
  unsigned short* wqkvb  = (unsigned short*)alloc((size_t)NQKV * 768 * 2);
  unsigned short* wprojb = (unsigned short*)alloc((size_t)768 * 768 * 2);
  unsigned short* qb     = (unsigned short*)alloc((size_t)B_ * H_ * NPAD * HD_ * 2);
  unsigned short* kbuf   = (unsigned short*)alloc((size_t)B_ * H_ * NPAD * HD_ * 2);
  unsigned short* vtb    = (unsigned short*)alloc((size_t)B_ * H_ * HD_ * NPAD * 2);
  unsigned short* ob     = (unsigned short*)alloc((size_t)MPAD * 768 * 2);
  (void)ob;

  // Zero only vtb's tail 64-col group (3.1 MB): the sole region that meets
  // exact-zero P slots in MFMA (0*NaN hazard). All other pads are discarded
  // arithmetically (dot-product row/col independence + output guards).
  zero_vtb_tail<<<768, 256, 0, stream>>>(vtb);

  {
    int n4 = (B_ * N_ * C_) / 4;
    cvt_f32_bf16<<<(n4 + 255) / 256, 256, 0, stream>>>(x, xb, n4);
    n4 = (NQKV * C_) / 4;
    cvt_f32_bf16<<<(n4 + 255) / 256, 256, 0, stream>>>(Wqkv, wqkvb, n4);
    n4 = (C_ * C_) / 4;
    cvt_f32_bf16<<<(n4 + 255) / 256, 256, 0, stream>>>(Wproj, wprojb, n4);
  }

  gemm_qkv<<<dim3(MPAD / 128, NQKV / 128), 256, 0, stream>>>(xb, wqkvb, qb, kbuf, vtb);

  attn_kernel<<<dim3(10, B_ * H_), 256, 0, stream>>>(qb, kbuf, vtb, prev,
                                                     out + OUT0_ELTS, ob);

  gemm_proj<<<dim3(MPAD / 128, C_ / 128), 256, 0, stream>>>(ob, wprojb, bproj, out);
}